// Round 11
// baseline (208.050 us; speedup 1.0000x reference)
//
#include <hip/hip_runtime.h>
#include <hip/hip_bf16.h>

#define B_  256
#define H_  1024
#define D_  256
#define G_  32
#define C_  16
#define O_  256
#define HD_ 1280          // H + D
#define N1_ 16384         // C*H
#define RS_ 36            // LDS row stride in shorts (72 B = 18 banks; uniform
                          // 2-way = free)

typedef __attribute__((ext_vector_type(8))) short short8;
typedef __attribute__((ext_vector_type(4))) short s16x4;
typedef __attribute__((ext_vector_type(4))) float f32x4;

#define MFMA16(a, b, c) __builtin_amdgcn_mfma_f32_16x16x32_bf16((a), (b), (c), 0, 0, 0)

// tanh via fast exp + hw rcp; clamped to +-(1-6e-8) so that the downstream
// blend denominator 1 + tA*tB is always > 0 (never 0*inf = NaN).
__device__ __forceinline__ float tanh_c(float x) {
    float y = __expf(2.f * x);
    float t = 1.f - 2.f * __builtin_amdgcn_rcpf(y + 1.f);
    return fminf(fmaxf(t, -0.99999994f), 0.99999994f);
}

// Split fp32 into bf16 hi + bf16 lo (both truncated).
__device__ __forceinline__ short bfhi(float x) {
    return (short)(__float_as_uint(x) >> 16);
}
__device__ __forceinline__ short bflo(float x) {
    float fhi = __uint_as_float(__float_as_uint(x) & 0xFFFF0000u);
    return (short)(__float_as_uint(x - fhi) >> 16);
}

__device__ __forceinline__ void split4(const float4 v, s16x4& hi, s16x4& lo) {
    hi[0] = bfhi(v.x); lo[0] = bflo(v.x);
    hi[1] = bfhi(v.y); lo[1] = bflo(v.y);
    hi[2] = bfhi(v.z); lo[2] = bflo(v.z);
    hi[3] = bfhi(v.w); lo[3] = bflo(v.w);
}

// ---------------------------------------------------------------------------
// Kernel 1: tA[b, c*H+o] = tanh( sum_h hidden[b,h]*attn_w[c,o,h] + attn_b[c,o] )
// GEMM: M=256, N=16384, K=1024, fp32 in/out, 3-term bf16-split MFMA.
// 128x128 block tile, 512 threads = 8 waves of 64(M)x32(N) (2m x 4n grid).
// Rationale: LDS port was the bottleneck (2119 of 3825 cy/iter at the old
// 32x32 wave tile). Fragment reads scale as Mw+Nw, MFMA work as Mw*Nw:
// 64x32 waves cut LDS-cy/work 2.75x. Grid (2,128) = 1 block/CU (25% occ --
// accepted; register prefetch covers global latency).
// ---------------------------------------------------------------------------
__global__ __launch_bounds__(512) void gemm1_kernel(
    const float* __restrict__ hidden, const float* __restrict__ attn_w,
    const float* __restrict__ attn_b, float* __restrict__ hp)
{
    __shared__ short AsH[128 * RS_];   // [row][k], padded stride
    __shared__ short AsL[128 * RS_];
    __shared__ short BsH[128 * RS_];
    __shared__ short BsL[128 * RS_];

    const int tid  = threadIdx.x;
    const int wave = tid >> 6, lane = tid & 63;
    const int m0 = blockIdx.x * 128;   // 2 m-tiles (fast axis, shares B strip)
    const int n0 = blockIdx.y * 128;   // 128 n-tiles
    const int wm = (wave >> 2) * 64;   // 2m x 4n wave grid, each wave 64x32
    const int wn = (wave & 3) * 32;
    const int l16 = lane & 15;
    const int lk  = (lane >> 4) * 8;

    f32x4 acc[4][2];
    #pragma unroll
    for (int mi = 0; mi < 4; ++mi)
        #pragma unroll
        for (int ni = 0; ni < 2; ++ni)
            acc[mi][ni] = f32x4{0.f, 0.f, 0.f, 0.f};

    // A-tile and B-tile each 128x32 floats = 1024 float4-chunks; 2/thread each.
    int rr[2], cc[2];
    #pragma unroll
    for (int i = 0; i < 2; ++i) {
        const int chunk = tid + i * 512;
        rr[i] = chunk >> 3;
        cc[i] = (chunk & 7) * 4;
    }

    const float* pA0 = hidden + (m0 + rr[0]) * H_ + cc[0];
    const float* pA1 = hidden + (m0 + rr[1]) * H_ + cc[1];
    const float* pB0 = attn_w + (size_t)(n0 + rr[0]) * HD_ + cc[0];
    const float* pB1 = attn_w + (size_t)(n0 + rr[1]) * HD_ + cc[1];

    // prologue: load k=0
    float4 va[2], vb[2];
    va[0] = *(const float4*)(pA0);
    va[1] = *(const float4*)(pA1);
    vb[0] = *(const float4*)(pB0);
    vb[1] = *(const float4*)(pB1);

    for (int k0 = 0; k0 < H_; k0 += 32) {
        __syncthreads();               // previous iter's fragment reads done
        #pragma unroll
        for (int i = 0; i < 2; ++i) {
            s16x4 h, l;
            split4(va[i], h, l);
            *(s16x4*)(AsH + rr[i] * RS_ + cc[i]) = h;
            *(s16x4*)(AsL + rr[i] * RS_ + cc[i]) = l;
            split4(vb[i], h, l);
            *(s16x4*)(BsH + rr[i] * RS_ + cc[i]) = h;
            *(s16x4*)(BsL + rr[i] * RS_ + cc[i]) = l;
        }
        __syncthreads();               // stores visible to all waves

        // prefetch next K-slab while this slab's MFMAs run
        if (k0 + 32 < H_) {
            const int kn = k0 + 32;
            va[0] = *(const float4*)(pA0 + kn);
            va[1] = *(const float4*)(pA1 + kn);
            vb[0] = *(const float4*)(pB0 + kn);
            vb[1] = *(const float4*)(pB1 + kn);
        }

        short8 ah[4], al[4], bh[2], bl[2];
        #pragma unroll
        for (int mi = 0; mi < 4; ++mi) {
            ah[mi] = *(const short8*)(AsH + (wm + mi * 16 + l16) * RS_ + lk);
            al[mi] = *(const short8*)(AsL + (wm + mi * 16 + l16) * RS_ + lk);
        }
        #pragma unroll
        for (int ni = 0; ni < 2; ++ni) {
            bh[ni] = *(const short8*)(BsH + (wn + ni * 16 + l16) * RS_ + lk);
            bl[ni] = *(const short8*)(BsL + (wn + ni * 16 + l16) * RS_ + lk);
        }
        #pragma unroll
        for (int mi = 0; mi < 4; ++mi)
            #pragma unroll
            for (int ni = 0; ni < 2; ++ni) {
                acc[mi][ni] = MFMA16(ah[mi], bh[ni], acc[mi][ni]);
                acc[mi][ni] = MFMA16(al[mi], bh[ni], acc[mi][ni]);
                acc[mi][ni] = MFMA16(ah[mi], bl[ni], acc[mi][ni]);
            }
    }

    // C/D layout: col = lane&15, row = (lane>>4)*4 + reg.  Store tanh(val).
    const int lr = (lane >> 4) * 4;
    #pragma unroll
    for (int mi = 0; mi < 4; ++mi) {
        #pragma unroll
        for (int ni = 0; ni < 2; ++ni) {
            const int col  = n0 + wn + ni * 16 + l16;
            const float bias = attn_b[col];
            float* dst = hp + (size_t)(m0 + wm + mi * 16 + lr) * N1_ + col;
            f32x4 vacc = acc[mi][ni];
            dst[0]        = tanh_c(vacc[0] + bias);
            dst[N1_]      = tanh_c(vacc[1] + bias);
            dst[2 * N1_]  = tanh_c(vacc[2] + bias);
            dst[3 * N1_]  = tanh_c(vacc[3] + bias);
        }
    }
}

// ---------------------------------------------------------------------------
// Kernel 2: tB[c,g,o] = tanh( sum_d enc[c,g,d] * attn_w[c,o,H+d] )
// Per-c GEMM: M=32, N=1024, K=256; grid (16,16)=256 blocks.
// ---------------------------------------------------------------------------
__global__ __launch_bounds__(256) void gemm2_kernel(
    const float* __restrict__ enc, const float* __restrict__ attn_w,
    float* __restrict__ ep)
{
    const int tid  = threadIdx.x;
    const int wave = tid >> 6, lane = tid & 63;
    const int c  = blockIdx.y;
    const int n0 = blockIdx.x * 64 + wave * 16;   // o tile, 16 per wave
    const int l16 = lane & 15;
    const int lk  = (lane >> 4) * 8;

    f32x4 acc[2];
    acc[0] = f32x4{0.f, 0.f, 0.f, 0.f};
    acc[1] = f32x4{0.f, 0.f, 0.f, 0.f};

    const float* encp = enc + c * (G_ * D_);
    const float* wp   = attn_w + (size_t)c * H_ * HD_ + H_;

    #pragma unroll
    for (int kk = 0; kk < 8; ++kk) {
        const int k0 = kk * 32 + lk;
        short8 ah[2], al[2], bh, bl;
        #pragma unroll
        for (int mi = 0; mi < 2; ++mi) {
            const float* p = encp + (mi * 16 + l16) * D_ + k0;
            s16x4 h0, l0, h1, l1;
            split4(*(const float4*)p, h0, l0);
            split4(*(const float4*)(p + 4), h1, l1);
            ah[mi] = short8{h0[0],h0[1],h0[2],h0[3],h1[0],h1[1],h1[2],h1[3]};
            al[mi] = short8{l0[0],l0[1],l0[2],l0[3],l1[0],l1[1],l1[2],l1[3]};
        }
        {
            const float* p = wp + (size_t)(n0 + l16) * HD_ + k0;
            s16x4 h0, l0, h1, l1;
            split4(*(const float4*)p, h0, l0);
            split4(*(const float4*)(p + 4), h1, l1);
            bh = short8{h0[0],h0[1],h0[2],h0[3],h1[0],h1[1],h1[2],h1[3]};
            bl = short8{l0[0],l0[1],l0[2],l0[3],l1[0],l1[1],l1[2],l1[3]};
        }
        #pragma unroll
        for (int mi = 0; mi < 2; ++mi) {
            acc[mi] = MFMA16(ah[mi], bh, acc[mi]);
            acc[mi] = MFMA16(al[mi], bh, acc[mi]);
            acc[mi] = MFMA16(ah[mi], bl, acc[mi]);
        }
    }

    const int lr = (lane >> 4) * 4;
    #pragma unroll
    for (int mi = 0; mi < 2; ++mi) {
        const int g = mi * 16 + lr;
        const int o = n0 + l16;
        float* dst = ep + (c * G_ + g) * H_ + o;
        f32x4 vacc = acc[mi];
        dst[0]      = tanh_c(vacc[0]);
        dst[H_]     = tanh_c(vacc[1]);
        dst[2 * H_] = tanh_c(vacc[2]);
        dst[3 * H_] = tanh_c(vacc[3]);
    }
}

// ---------------------------------------------------------------------------
// Kernel 3: per (c, 4 b's): scores[b,g] = sum_h blend(tA,tB)*v, where
// blend = (tA+tB)/(1+tA*tB) = tanh(A+B); softmax over g; att_cat; weighted.
// b-tile of 4 amortizes the ep (tB) and enc loads 4x -- ep L2 traffic was the
// gap between measured ~50us and the ~27us VALU floor.
// Grid (C_, B_/4) = (16,64) = 1024 blocks = 4 blocks/CU.
// ---------------------------------------------------------------------------
__global__ __launch_bounds__(256) void attn_kernel(
    const float* __restrict__ hp, const float* __restrict__ ep,
    const float* __restrict__ v, const float* __restrict__ enc,
    float* __restrict__ out, float* __restrict__ wt)
{
    const int c  = blockIdx.x;
    const int b0 = blockIdx.y * 4;
    const int tid  = threadIdx.x;
    const int wave = tid >> 6, lane = tid & 63;

    __shared__ float s_att[4][G_];
    __shared__ float s_sc[G_][4];

    float tav[4][16], vv[16];
    const float* vrow = v + c * H_;
    #pragma unroll
    for (int j = 0; j < 16; ++j) {
        const int o = lane + j * 64;
        vv[j] = vrow[o];
        #pragma unroll
        for (int bi = 0; bi < 4; ++bi)
            tav[bi][j] = hp[(size_t)(b0 + bi) * N1_ + c * H_ + o];
    }

    #pragma unroll
    for (int gg = 0; gg < 8; ++gg) {
        const int g = wave * 8 + gg;
        const float* eprow = ep + (c * G_ + g) * H_;
        float s[4] = {0.f, 0.f, 0.f, 0.f};
        #pragma unroll
        for (int j = 0; j < 16; ++j) {
            const float tb = eprow[lane + j * 64];
            #pragma unroll
            for (int bi = 0; bi < 4; ++bi) {
                const float ta  = tav[bi][j];
                const float den = fmaf(ta, tb, 1.f);
                const float r   = __builtin_amdgcn_rcpf(den);
                s[bi] = fmaf((ta + tb) * r, vv[j], s[bi]);
            }
        }
        #pragma unroll
        for (int off = 32; off > 0; off >>= 1)
            #pragma unroll
            for (int bi = 0; bi < 4; ++bi)
                s[bi] += __shfl_down(s[bi], off, 64);
        if (lane == 0) {
            #pragma unroll
            for (int bi = 0; bi < 4; ++bi)
                s_sc[g][bi] = s[bi];
        }
    }
    __syncthreads();

    if (tid < 128) {   // 4 groups of 32: bi = tid>>5, g = tid&31
        const int bi = tid >> 5, gl = tid & 31;
        float s = s_sc[gl][bi];
        float m = s;
        #pragma unroll
        for (int off = 16; off > 0; off >>= 1)
            m = fmaxf(m, __shfl_xor(m, off, 32));
        const float e = __expf(s - m);
        float sum = e;
        #pragma unroll
        for (int off = 16; off > 0; off >>= 1)
            sum += __shfl_xor(sum, off, 32);
        const float a = e / sum;
        s_att[bi][gl] = a;
        out[(size_t)(b0 + bi) * (C_ * G_) + c * G_ + gl] = a;   // att_cat
    }
    __syncthreads();

    // weighted[b,c,d], thread = d; enc element loaded once, reused 4x
    float w[4] = {0.f, 0.f, 0.f, 0.f};
    const float* encc = enc + c * (G_ * D_) + tid;
    #pragma unroll
    for (int g = 0; g < G_; ++g) {
        const float e = encc[g * D_];
        #pragma unroll
        for (int bi = 0; bi < 4; ++bi)
            w[bi] = fmaf(s_att[bi][g], e, w[bi]);
    }
    #pragma unroll
    for (int bi = 0; bi < 4; ++bi)
        wt[(size_t)((b0 + bi) * C_ + c) * D_ + tid] = w[bi];
}

// ---------------------------------------------------------------------------
// Kernel 4: pooled[b,d] = mean_c weighted; out[b,o] = pooled.out_w[o,:] + out_b
// ---------------------------------------------------------------------------
__global__ __launch_bounds__(256) void out_kernel(
    const float* __restrict__ wt, const float* __restrict__ out_w,
    const float* __restrict__ out_b, float* __restrict__ out)
{
    const int b = blockIdx.x, tid = threadIdx.x;
    __shared__ float pooled[D_];

    float s = 0.f;
    #pragma unroll
    for (int c = 0; c < C_; ++c)
        s += wt[(size_t)(b * C_ + c) * D_ + tid];
    pooled[tid] = s * (1.f / 16.f);
    __syncthreads();

    float acc = out_b[tid];
    const float* wrow = out_w + tid * D_;
    #pragma unroll 8
    for (int dc = 0; dc < 64; ++dc) {
        float4 w4 = *(const float4*)(wrow + dc * 4);
        acc += pooled[dc * 4 + 0] * w4.x;
        acc += pooled[dc * 4 + 1] * w4.y;
        acc += pooled[dc * 4 + 2] * w4.z;
        acc += pooled[dc * 4 + 3] * w4.w;
    }
    out[(size_t)B_ * (C_ * G_) + b * O_ + tid] = acc;
}

extern "C" void kernel_launch(void* const* d_in, const int* in_sizes, int n_in,
                              void* d_out, int out_size, void* d_ws, size_t ws_size,
                              hipStream_t stream) {
    const float* hidden = (const float*)d_in[0];   // (B,H)     fp32
    const float* enc    = (const float*)d_in[1];   // (C,G,D)   fp32
    const float* attn_w = (const float*)d_in[2];   // (C,H,H+D) fp32
    const float* attn_b = (const float*)d_in[3];   // (C,H)     fp32
    const float* v      = (const float*)d_in[4];   // (C,H)     fp32
    const float* out_w  = (const float*)d_in[5];   // (O,D)     fp32
    const float* out_b  = (const float*)d_in[6];   // (O,)      fp32
    float* out = (float*)d_out;                    // att_cat (B,C*G) ++ out (B,O)

    float* hp = (float*)d_ws;                      // (B, C*H)  tA, fp32: 16.78 MB
    float* ep = hp + (size_t)B_ * N1_;             // (C, G, H) tB, fp32:  2.10 MB
    float* wt = ep + (size_t)C_ * G_ * H_;         // (B, C, D) fp32:      4.19 MB

    gemm1_kernel<<<dim3(2, 128), 512, 0, stream>>>(hidden, attn_w, attn_b, hp);
    gemm2_kernel<<<dim3(16, C_), 256, 0, stream>>>(enc, attn_w, ep);
    attn_kernel<<<dim3(C_, B_ / 4), 256, 0, stream>>>(hp, ep, v, enc, out, wt);
    out_kernel<<<B_, 256, 0, stream>>>(wt, out_w, out_b, out);
}